// Round 2
// baseline (203.578 us; speedup 1.0000x reference)
//
#include <hip/hip_runtime.h>
#include <math.h>

#define TOTAL 200      // distance bins (STOP/DELTA)
#define TB    32       // tile columns
#define BLK   256      // threads per block = tile rows
#define NW    4        // waves per block
#define GRID  2048     // persistent blocks: 8/CU x 256 CU
#define NR    16       // replicated global histograms
#define RATIO (BLK/TB) // 8: cbMin(rb) = RATIO*rb for self-pair triangles

typedef float f32x4 __attribute__((ext_vector_type(4)));

// ---------------------------------------------------------------------------
// prep: scale positions, pack float4{x,y,z,|p|^2}; zero NR replicated global
// histograms PLUS the done-counter word (ghist[NR*3*TOTAL]).
// ---------------------------------------------------------------------------
__global__ void rdf_prep(const float* __restrict__ p0, const float* __restrict__ p1,
                         const float* __restrict__ rs,
                         float4* __restrict__ b0, float4* __restrict__ b1,
                         unsigned int* __restrict__ ghist, int n0, int n1)
{
    const float sx = rs[0], sy = rs[1], sz = rs[2];
    int t = blockIdx.x * blockDim.x + threadIdx.x;
    if (t < n0) {
        float x = p0[t*3+0]*sx, y = p0[t*3+1]*sy, z = p0[t*3+2]*sz;
        b0[t] = make_float4(x, y, z, x*x + y*y + z*z);
    } else if (t < n0 + n1) {
        int u = t - n0;
        float x = p1[u*3+0]*sx, y = p1[u*3+1]*sy, z = p1[u*3+2]*sz;
        b1[u] = make_float4(x, y, z, x*x + y*y + z*z);
    }
    if (t < NR * 3 * TOTAL + 1) ghist[t] = 0;   // 9601 words <= grid threads
}

// ---------------------------------------------------------------------------
// one pair: EXACT arithmetic tree of the verified kernel (absmax 0.0):
//   d2 = (a2 + b.w) - 2*dot ; v = sqrt(max(d2,0))*20 ; bin = (int)v
// ---------------------------------------------------------------------------
template<bool DIAG>
__device__ __forceinline__ void pair_one(f32x4 q, int J,
                                         float ax, float ay, float az, float a2,
                                         unsigned int* __restrict__ mylh, int ofs)
{
    float dot = ax*q.x + ay*q.y + az*q.z;
    float d2  = (a2 + q.w) - 2.0f*dot;
    float v   = __builtin_amdgcn_sqrtf(fmaxf(d2, 0.0f)) * 20.0f;
    bool ok   = (v < 200.0f);
    if (DIAG) ok = ok && (J > ofs);
    if (ok) atomicAdd(&mylh[(int)v], 1u);
}

template<bool DIAG>
__device__ __forceinline__ void compute4(f32x4 q0, f32x4 q1, f32x4 q2, f32x4 q3, int jb,
                                         float ax, float ay, float az, float a2,
                                         unsigned int* __restrict__ mylh, int ofs)
{
    pair_one<DIAG>(q0, jb+0, ax, ay, az, a2, mylh, ofs);
    pair_one<DIAG>(q1, jb+1, ax, ay, az, a2, mylh, ofs);
    pair_one<DIAG>(q2, jb+2, ax, ay, az, a2, mylh, ofs);
    pair_one<DIAG>(q3, jb+3, ax, ay, az, a2, mylh, ofs);
}

// ---------------------------------------------------------------------------
// depth-2 pipelined B loads (T4 counted-vmcnt idiom). The wait for batch k is
// inside the asm that ISSUES batch k+1 ("vmcnt(4)" = <=4 outstanding = k done).
// Previous batch regs are tied "+v" through the waiting asm so no use can be
// hoisted above the wait. Round-1's vmcnt(0)+sched_barrier structure exposed
// full latency per batch by construction (that's why it didn't move) — here
// load latency overlaps the previous batch's ~120-cycle compute.
// Macros reference in-scope `voff` (uniform tile byte base) and `Bb`.
// ---------------------------------------------------------------------------
#define ISSUE4(q0,q1,q2,q3, o0,o1,o2,o3)                                 \
    asm volatile(                                                        \
        "global_load_dwordx4 %0, %4, %5 offset:" o0 "\n\t"               \
        "global_load_dwordx4 %1, %4, %5 offset:" o1 "\n\t"               \
        "global_load_dwordx4 %2, %4, %5 offset:" o2 "\n\t"               \
        "global_load_dwordx4 %3, %4, %5 offset:" o3                      \
        : "=&v"(q0), "=&v"(q1), "=&v"(q2), "=&v"(q3)                     \
        : "v"(voff), "s"(Bb))

#define ISSUE4_WAIT4(q0,q1,q2,q3, p0,p1,p2,p3, o0,o1,o2,o3)              \
    asm volatile(                                                        \
        "global_load_dwordx4 %0, %8, %9 offset:" o0 "\n\t"               \
        "global_load_dwordx4 %1, %8, %9 offset:" o1 "\n\t"               \
        "global_load_dwordx4 %2, %8, %9 offset:" o2 "\n\t"               \
        "global_load_dwordx4 %3, %8, %9 offset:" o3 "\n\t"               \
        "s_waitcnt vmcnt(4)"                                             \
        : "=&v"(q0), "=&v"(q1), "=&v"(q2), "=&v"(q3),                    \
          "+v"(p0), "+v"(p1), "+v"(p2), "+v"(p3)                         \
        : "v"(voff), "s"(Bb))

#define WAIT_ALL(p0,p1,p2,p3)                                            \
    asm volatile("s_waitcnt vmcnt(0)"                                    \
        : "+v"(p0), "+v"(p1), "+v"(p2), "+v"(p3))

template<bool DIAG>
__device__ __forceinline__ void pair_loop(const f32x4* __restrict__ Bb, int colBase,
                                          float ax, float ay, float az, float a2,
                                          unsigned int* __restrict__ mylh, int ofs)
{
    unsigned voff = (unsigned)colBase * 16u;
    f32x4 A0,A1,A2,A3, B0,B1,B2,B3;
    ISSUE4      (A0,A1,A2,A3,             "0","16","32","48");
    ISSUE4_WAIT4(B0,B1,B2,B3, A0,A1,A2,A3, "64","80","96","112");
    compute4<DIAG>(A0,A1,A2,A3,  0, ax,ay,az,a2, mylh, ofs);
    ISSUE4_WAIT4(A0,A1,A2,A3, B0,B1,B2,B3, "128","144","160","176");
    compute4<DIAG>(B0,B1,B2,B3,  4, ax,ay,az,a2, mylh, ofs);
    ISSUE4_WAIT4(B0,B1,B2,B3, A0,A1,A2,A3, "192","208","224","240");
    compute4<DIAG>(A0,A1,A2,A3,  8, ax,ay,az,a2, mylh, ofs);
    ISSUE4_WAIT4(A0,A1,A2,A3, B0,B1,B2,B3, "256","272","288","304");
    compute4<DIAG>(B0,B1,B2,B3, 12, ax,ay,az,a2, mylh, ofs);
    ISSUE4_WAIT4(B0,B1,B2,B3, A0,A1,A2,A3, "320","336","352","368");
    compute4<DIAG>(A0,A1,A2,A3, 16, ax,ay,az,a2, mylh, ofs);
    ISSUE4_WAIT4(A0,A1,A2,A3, B0,B1,B2,B3, "384","400","416","432");
    compute4<DIAG>(B0,B1,B2,B3, 20, ax,ay,az,a2, mylh, ofs);
    ISSUE4_WAIT4(B0,B1,B2,B3, A0,A1,A2,A3, "448","464","480","496");
    compute4<DIAG>(A0,A1,A2,A3, 24, ax,ay,az,a2, mylh, ofs);
    WAIT_ALL(B0,B1,B2,B3);
    compute4<DIAG>(B0,B1,B2,B3, 28, ax,ay,az,a2, mylh, ofs);
}

// ---------------------------------------------------------------------------
// flush the single-type LDS histogram to this block's replica and re-zero.
// Uniform call sites only (type changes are block-uniform).
// ---------------------------------------------------------------------------
__device__ __forceinline__ void flush_and_zero(unsigned int (*lh)[2][TOTAL],
                                               unsigned int* __restrict__ gh,
                                               int type, int tid)
{
    __syncthreads();                       // all waves' ds_adds drained
    if (tid < TOTAL) {
        unsigned int c = 0;
        #pragma unroll
        for (int w = 0; w < NW; ++w) c += lh[w][0][tid] + lh[w][1][tid];
        if (c) atomicAdd(&gh[type*TOTAL + tid], (type == 1) ? c : 2u*c);
    }
    __syncthreads();                       // reads done before zeroing
    uint4* z = (uint4*)lh;
    for (int k = tid; k < NW*2*TOTAL/4; k += BLK) z[k] = make_uint4(0,0,0,0);
    __syncthreads();
}

// ---------------------------------------------------------------------------
// persistent pair-histogram kernel. Tile list (triangle pre-applied):
//   [0,T0)   : b0 x b0 self -> hist 0, doubled
//   [T0,T01) : b0 x b1 cross -> hist 1
//   [T01,Tt) : b1 x b1 self -> hist 2, doubled
// LDS hist is now SINGLE-type, [wave][parity]-private: 6.4 KB (was 19.2 KB) —
// contiguous tile chunks cross a type boundary <=2x, flush on change.
// Last block (device done-counter) performs the normalization: one fewer
// kernel launch in the fixed overhead.
// ---------------------------------------------------------------------------
__global__ __launch_bounds__(BLK, 8) void rdf_hist(
    const float4* __restrict__ b0, const float4* __restrict__ b1,
    unsigned int* __restrict__ ghist, unsigned int* __restrict__ done,
    const float* __restrict__ count, const float* __restrict__ rs,
    float* __restrict__ out,
    int n0, int n1, int T0, int T01, int Ttot,
    int cb0, int cb1, int rows0, int rows1)
{
    __shared__ unsigned int lh[NW][2][TOTAL];   // 6.4 KB
    __shared__ unsigned int lastFlag;

    const int tid  = threadIdx.x;
    const int wave = tid >> 6;
    const int par  = tid & 1;

    uint4* z = (uint4*)lh;
    for (int k = tid; k < NW*2*TOTAL/4; k += BLK) z[k] = make_uint4(0,0,0,0);
    __syncthreads();

    unsigned int* gh   = ghist + (blockIdx.x & (NR - 1)) * (3 * TOTAL);
    unsigned int* mylh = &lh[wave][par][0];

    const int gBeg = (int)(((long long)blockIdx.x       * Ttot) / GRID);
    const int gEnd = (int)(((long long)(blockIdx.x + 1) * Ttot) / GRID);

    int curType = -1;
    for (int g = gBeg; g < gEnd; ++g) {
        // ---- decode tile id -> (type, rb, cb); block-uniform scalar math
        int type, rb, cb;
        if (g < T0) {
            type = 0; rb = 0;
            while (rb + 1 < rows0 && (cb0*(rb+1) - (RATIO/2)*(rb+1)*rb) <= g) ++rb;
            cb = RATIO*rb + (g - (cb0*rb - (RATIO/2)*rb*(rb-1)));
        } else if (g < T01) {
            int u = g - T0; type = 1; rb = u / cb1; cb = u - rb*cb1;
        } else {
            int u = g - T01; type = 2; rb = 0;
            while (rb + 1 < rows1 && (cb1*(rb+1) - (RATIO/2)*(rb+1)*rb) <= u) ++rb;
            cb = RATIO*rb + (u - (cb1*rb - (RATIO/2)*rb*(rb-1)));
        }
        if (type != curType) {
            if (curType >= 0) flush_and_zero(lh, gh, curType, tid);
            curType = type;
        }
        const f32x4* Ab = (const f32x4*)((type == 2) ? b1 : b0);
        const f32x4* Bb = (const f32x4*)((type == 0) ? b0 : b1);
        const int nA    = (type == 2) ? n1 : n0;

        const int rowBase = rb * BLK;
        const int colBase = cb * TB;
        const int aIdx    = rowBase + tid;

        // A row via asm + vmcnt(0): also drains any pending flush atomics so
        // the pipelined vmcnt(4) counting inside pair_loop is exact.
        int aSafe = (aIdx < nA) ? aIdx : 0;
        unsigned aoff = (unsigned)aSafe * 16u;
        f32x4 av;
        asm volatile("global_load_dwordx4 %0, %1, %2\n\t"
                     "s_waitcnt vmcnt(0)"
                     : "=&v"(av) : "v"(aoff), "s"(Ab));
        float a2 = (aIdx < nA) ? av.w : 3.0e18f;   // pad row -> no bins

        const bool diag = (type != 1) && (colBase < rowBase + BLK);
        if (diag) pair_loop<true >(Bb, colBase, av.x, av.y, av.z, a2, mylh, aIdx - colBase);
        else      pair_loop<false>(Bb, colBase, av.x, av.y, av.z, a2, mylh, 0);
    }
    if (curType >= 0) flush_and_zero(lh, gh, curType, tid);

    // ---- folded finalize: last block normalizes (fence + device atomics)
    __threadfence();
    if (tid == 0) lastFlag = atomicAdd(done, 1u);
    __syncthreads();
    if (lastFlag == GRID - 1) {
        __threadfence();
        float vol = rs[0]*rs[1]*rs[2];
        for (int t = tid; t < 2*2*TOTAL; t += BLK) {
            int k = t % TOTAL;
            int j = (t / TOTAL) & 1;
            int i = t / (2*TOTAL);
            int Na = (i == 0) ? n0 : n1;
            int Nb = (j == 0) ? n0 : n1;
            int hidx = (i == j) ? (i == 0 ? 0 : 2) : 1;
            unsigned int c = 0;
            #pragma unroll
            for (int r = 0; r < NR; ++r)
                c += atomicAdd(&ghist[r*3*TOTAL + hidx*TOTAL + k], 0u); // coherent read
            double sv  = ((0.025 + (double)k * 0.05) * 0.05) * 2.0 * M_PI * 3.0;
            float  svf = (float)sv;
            float  density = (float)Nb / vol;
            float  rr = (((float)c / density) / svf) / (float)Na;
            out[t] = count[t] + rr;
        }
    }
}

extern "C" void kernel_launch(void* const* d_in, const int* in_sizes, int n_in,
                              void* d_out, int out_size, void* d_ws, size_t ws_size,
                              hipStream_t stream) {
    const float* pos0  = (const float*)d_in[0];
    const float* pos1  = (const float*)d_in[1];
    const float* count = (const float*)d_in[2];
    const float* rs    = (const float*)d_in[3];
    float* out = (float*)d_out;

    int n0 = in_sizes[0] / 3;   // 4096
    int n1 = in_sizes[1] / 3;   // 8192

    // ws layout: [ghist NR*3*200 u32][done u32] (38.4KB+4) | pad 40KB | b0 | b1
    unsigned int* ghist = (unsigned int*)d_ws;
    unsigned int* done  = ghist + NR*3*TOTAL;
    float4* b0 = (float4*)((char*)d_ws + 40960);
    float4* b1 = b0 + n0;

    int prepBlocks = (n0 + n1 + BLK - 1) / BLK;   // 12288 threads >= 9601 words
    rdf_prep<<<prepBlocks, BLK, 0, stream>>>(pos0, pos1, rs, b0, b1, ghist, n0, n1);

    int rows0 = (n0 + BLK - 1) / BLK;   // 16
    int rows1 = (n1 + BLK - 1) / BLK;   // 32
    int cb0   = (n0 + TB - 1) / TB;     // 128
    int cb1   = (n1 + TB - 1) / TB;     // 256
    int T0   = cb0*rows0 - (RATIO/2)*rows0*(rows0-1);   // 1088
    int Tc   = rows0*cb1;                               // 4096
    int T2   = cb1*rows1 - (RATIO/2)*rows1*(rows1-1);   // 4224
    int T01  = T0 + Tc;
    int Ttot = T01 + T2;                                // 9408

    rdf_hist<<<GRID, BLK, 0, stream>>>(b0, b1, ghist, done, count, rs, out,
                                       n0, n1, T0, T01, Ttot, cb0, cb1, rows0, rows1);
}

// Round 3
// 104.672 us; speedup vs baseline: 1.9449x; 1.9449x over previous
//
#include <hip/hip_runtime.h>
#include <math.h>

#define TOTAL 200      // distance bins (STOP/DELTA)
#define TB    32       // tile columns
#define BLK   256      // threads per block = tile rows
#define NW    4        // waves per block
#define GRID  2048     // persistent blocks: 8/CU x 256 CU
#define NR    16       // replicated global histograms
#define RATIO (BLK/TB) // 8: cbMin(rb) = RATIO*rb for self-pair triangles

// ---------------------------------------------------------------------------
// prep: scale positions by real_size, pack float4{x,y,z,|p|^2}; zero the NR
// replicated global histograms. Same-stream ordering covers rdf_hist.
// (verbatim from the verified 47.5us round-0 kernel)
// ---------------------------------------------------------------------------
__global__ void rdf_prep(const float* __restrict__ p0, const float* __restrict__ p1,
                         const float* __restrict__ rs,
                         float4* __restrict__ b0, float4* __restrict__ b1,
                         unsigned int* __restrict__ ghist, int n0, int n1)
{
    const float sx = rs[0], sy = rs[1], sz = rs[2];
    int t = blockIdx.x * blockDim.x + threadIdx.x;
    if (t < n0) {
        float x = p0[t*3+0]*sx, y = p0[t*3+1]*sy, z = p0[t*3+2]*sz;
        b0[t] = make_float4(x, y, z, x*x + y*y + z*z);
    } else if (t < n0 + n1) {
        int u = t - n0;
        float x = p1[u*3+0]*sx, y = p1[u*3+1]*sy, z = p1[u*3+2]*sz;
        b1[u] = make_float4(x, y, z, x*x + y*y + z*z);
    }
    if (t < NR * 3 * TOTAL) ghist[t] = 0;   // 9600 words <= grid threads
}

// ---------------------------------------------------------------------------
// tile-id decode (block-uniform scalar math), shared by compute + staging
// ---------------------------------------------------------------------------
struct Tile { int type, rb, cb; };

__device__ __forceinline__ Tile decode(int g, int T0, int T01,
                                       int cb0, int cb1, int rows0, int rows1)
{
    Tile t;
    if (g < T0) {
        t.type = 0; t.rb = 0;
        // offset(r) = cb0*r - (RATIO/2)*r*(r-1)
        while (t.rb + 1 < rows0 && (cb0*(t.rb+1) - (RATIO/2)*(t.rb+1)*t.rb) <= g) ++t.rb;
        t.cb = RATIO*t.rb + (g - (cb0*t.rb - (RATIO/2)*t.rb*(t.rb-1)));
    } else if (g < T01) {
        int u = g - T0; t.type = 1; t.rb = u / cb1; t.cb = u - t.rb*cb1;
    } else {
        int u = g - T01; t.type = 2; t.rb = 0;
        while (t.rb + 1 < rows1 && (cb1*(t.rb+1) - (RATIO/2)*(t.rb+1)*t.rb) <= u) ++t.rb;
        t.cb = RATIO*t.rb + (u - (cb1*t.rb - (RATIO/2)*t.rb*(t.rb-1)));
    }
    return t;
}

// ---------------------------------------------------------------------------
// inner pair loop — ARITHMETIC TREE VERBATIM from the verified round-0 kernel
// (absmax 0.0). Only change: Bs now points into LDS, so the per-j read is a
// ds_read_b128 at a wave-uniform address (broadcast, conflict-free). DS ops
// are IN-ORDER on the DS pipe, so the compiler's counted lgkmcnt(N) waits
// never have to drain the ds_add queue the way the old SMEM loads did (SMEM
// retires out-of-order wrt DS -> forced lgkmcnt(0) per use = round-0's wall).
// ---------------------------------------------------------------------------
template<bool DIAG>
__device__ __forceinline__ void pair_loop(const float4* __restrict__ Bs,
                                          float ax, float ay, float az, float a2,
                                          unsigned int* __restrict__ mylh, int ofs)
{
    #pragma unroll 8
    for (int j = 0; j < TB; ++j) {
        float4 b  = Bs[j];
        float dot = ax*b.x + ay*b.y + az*b.z;
        float d2  = (a2 + b.w) - 2.0f*dot;                    // reference identity
        float v   = __builtin_amdgcn_sqrtf(fmaxf(d2, 0.0f)) * 20.0f;
        bool ok   = (v < 200.0f);
        if (DIAG) ok = ok && (j > ofs);
        if (ok) atomicAdd(&mylh[(int)v], 1u);
    }
}

// ---------------------------------------------------------------------------
// persistent pair-histogram kernel. Round-0 structure (3-type private LDS
// hist, single flush at end) + NEW: double-buffered LDS staging of the B
// tile. One barrier per tile; staging of tile g+1 (global_load_dwordx4 +
// ds_write_b128 by threads 0..31) overlaps compute of tile g. WAR is safe:
// readers of Bst[(g+1)&1] ran at iter g-1 and passed the barrier at iter g.
// ---------------------------------------------------------------------------
__global__ __launch_bounds__(BLK) void rdf_hist(
    const float4* __restrict__ b0, const float4* __restrict__ b1,
    unsigned int* __restrict__ ghist,
    int n0, int n1, int T0, int T01, int Ttot,
    int cb0, int cb1, int rows0, int rows1)
{
    __shared__ unsigned int lh[3][NW][2][TOTAL];   // 19.2 KB
    __shared__ float4 Bst[2][TB];                  // 1 KB staging (double buffer)

    const int tid  = threadIdx.x;
    const int wave = tid >> 6;
    const int par  = tid & 1;

    // vectorized zero: 4800 words = 1200 uint4
    uint4* z = (uint4*)lh;
    for (int k = tid; k < 3*NW*2*TOTAL/4; k += BLK) z[k] = make_uint4(0,0,0,0);

    const int gBeg = (int)(((long long)blockIdx.x       * Ttot) / GRID);
    const int gEnd = (int)(((long long)(blockIdx.x + 1) * Ttot) / GRID);

    // prologue: stage first tile into buffer 0
    if (tid < TB) {
        Tile t0 = decode(gBeg, T0, T01, cb0, cb1, rows0, rows1);
        const float4* Bb = (t0.type == 0) ? b0 : b1;
        Bst[0][tid] = Bb[t0.cb * TB + tid];
    }

    for (int g = gBeg; g < gEnd; ++g) {
        __syncthreads();   // staging of Bst[p] complete (also covers hist zero)
        const int p = (g - gBeg) & 1;

        // overlap: stage NEXT tile into the other buffer while computing this one
        if (tid < TB && g + 1 < gEnd) {
            Tile tn = decode(g + 1, T0, T01, cb0, cb1, rows0, rows1);
            const float4* Bb = (tn.type == 0) ? b0 : b1;
            Bst[p ^ 1][tid] = Bb[tn.cb * TB + tid];
        }

        Tile t = decode(g, T0, T01, cb0, cb1, rows0, rows1);
        const float4* Ab = (t.type == 2) ? b1 : b0;
        const int nA     = (t.type == 2) ? n1 : n0;

        const int rowBase = t.rb * BLK;
        const int colBase = t.cb * TB;
        const int aIdx    = rowBase + tid;

        float4 a = (aIdx < nA) ? Ab[aIdx]
                               : make_float4(0.f, 0.f, 0.f, 3.0e18f); // pad row -> no bins
        unsigned int* mylh = &lh[t.type][wave][par][0];
        const float4* Bs   = &Bst[p][0];

        const bool diag = (t.type != 1) && (colBase < rowBase + BLK); // straddles diagonal
        if (diag) pair_loop<true >(Bs, a.x, a.y, a.z, a.w, mylh, aIdx - colBase);
        else      pair_loop<false>(Bs, a.x, a.y, a.z, a.w, mylh, 0);
    }
    __syncthreads();

    // one flush per block to its replica; self-pair hists doubled (triangle)
    unsigned int* gh = ghist + (blockIdx.x & (NR - 1)) * (3 * TOTAL);
    for (int k = tid; k < 3 * TOTAL; k += BLK) {
        int type = k / TOTAL, bin = k - type * TOTAL;
        unsigned int c = 0;
        #pragma unroll
        for (int w = 0; w < NW; ++w)
            { c += lh[type][w][0][bin] + lh[type][w][1][bin]; }
        if (c) atomicAdd(&gh[k], (type == 1) ? c : 2u * c);
    }
}

// ---------------------------------------------------------------------------
// normalize: out[i][j][k] = count[i][j][k] + h_ij[k]/density/SLICE_VOL[k]/Na
// (verbatim from the verified round-0 kernel)
// ---------------------------------------------------------------------------
__global__ void rdf_final(const unsigned int* __restrict__ ghist,
                          const float* __restrict__ count,
                          const float* __restrict__ rs,
                          float* __restrict__ out, int n0, int n1)
{
    int t = blockIdx.x * blockDim.x + threadIdx.x;
    if (t >= 2*2*TOTAL) return;
    int k = t % TOTAL;
    int j = (t / TOTAL) & 1;
    int i = t / (2*TOTAL);

    float vol = rs[0]*rs[1]*rs[2];
    int Na = (i == 0) ? n0 : n1;
    int Nb = (j == 0) ? n0 : n1;
    int hidx = (i == j) ? (i == 0 ? 0 : 2) : 1;

    unsigned int c = 0;
    #pragma unroll
    for (int r = 0; r < NR; ++r) c += ghist[r*3*TOTAL + hidx*TOTAL + k];

    double sv  = ((0.025 + (double)k * 0.05) * 0.05) * 2.0 * M_PI * 3.0; // fp64 SLICE_VOL
    float  svf = (float)sv;
    float  density = (float)Nb / vol;
    float  r = (((float)c / density) / svf) / (float)Na;
    out[t] = count[t] + r;
}

extern "C" void kernel_launch(void* const* d_in, const int* in_sizes, int n_in,
                              void* d_out, int out_size, void* d_ws, size_t ws_size,
                              hipStream_t stream) {
    const float* pos0  = (const float*)d_in[0];
    const float* pos1  = (const float*)d_in[1];
    const float* count = (const float*)d_in[2];
    const float* rs    = (const float*)d_in[3];
    float* out = (float*)d_out;

    int n0 = in_sizes[0] / 3;   // 4096
    int n1 = in_sizes[1] / 3;   // 8192

    // ws layout: [ghist NR*3*200 u32 = 38.4KB][pad to 40KB][b0][b1]
    unsigned int* ghist = (unsigned int*)d_ws;
    float4* b0 = (float4*)((char*)d_ws + 40960);
    float4* b1 = b0 + n0;

    int prepBlocks = (n0 + n1 + BLK - 1) / BLK;   // 12288 threads >= 9600 hist words
    rdf_prep<<<prepBlocks, BLK, 0, stream>>>(pos0, pos1, rs, b0, b1, ghist, n0, n1);

    int rows0 = (n0 + BLK - 1) / BLK;   // 16
    int rows1 = (n1 + BLK - 1) / BLK;   // 32
    int cb0   = (n0 + TB - 1) / TB;     // 128
    int cb1   = (n1 + TB - 1) / TB;     // 256
    // triangle tile counts: sum_r (cols - RATIO*r) = cols*rows - (RATIO/2)*rows*(rows-1)
    int T0   = cb0*rows0 - (RATIO/2)*rows0*(rows0-1);   // 1088
    int Tc   = rows0*cb1;                               // 4096
    int T2   = cb1*rows1 - (RATIO/2)*rows1*(rows1-1);   // 4224
    int T01  = T0 + Tc;
    int Ttot = T01 + T2;                                // 9408

    rdf_hist<<<GRID, BLK, 0, stream>>>(b0, b1, ghist, n0, n1,
                                       T0, T01, Ttot, cb0, cb1, rows0, rows1);

    rdf_final<<<(2*2*TOTAL + BLK - 1) / BLK, BLK, 0, stream>>>(ghist, count, rs, out, n0, n1);
}